// Round 7
// baseline (238.879 us; speedup 1.0000x reference)
//
#include <hip/hip_runtime.h>

// Problem constants (B=4, C=256, H=W=56, heads=8)
#define NUM_G 8
#define HD    32
#define LSP   3136            // 56*56 = 49*64 exactly
#define BG    32
#define TPB   256
#define LOG2E 1.4426950408889634f

typedef short bf16x8 __attribute__((ext_vector_type(8)));
typedef float f32x4  __attribute__((ext_vector_type(4)));
typedef unsigned uint2v __attribute__((ext_vector_type(2)));
typedef unsigned uint4v __attribute__((ext_vector_type(4)));

union B8 { bf16x8 h; uint4v u; };
union U8 { bf16x8 h; uint2v u[2]; };

// ---- single-instruction 2^x via compiler-known lowering (hazards handled) ----
extern "C" __device__ float __ocml_native_exp2_f32(float);
__device__ __forceinline__ float fast_exp2(float x) {
#if __has_builtin(__builtin_amdgcn_exp2f)
    return __builtin_amdgcn_exp2f(x);
#else
    return __ocml_native_exp2_f32(x);     // lowers to llvm.amdgcn.exp2 -> v_exp_f32
#endif
}

// ---- packed f32x2 -> bf16x2 ----
__device__ __forceinline__ unsigned pk_bf16(float a, float b) {
#if __has_builtin(__builtin_amdgcn_cvt_pk_bf16_f32)
    typedef __bf16 bf16x2_t __attribute__((ext_vector_type(2)));
    bf16x2_t r = __builtin_amdgcn_cvt_pk_bf16_f32(a, b);
    unsigned u; __builtin_memcpy(&u, &r, 4); return u;
#else
    unsigned ua = __float_as_uint(a); ua += 0x7FFFu + ((ua >> 16) & 1u);
    unsigned ub = __float_as_uint(b); ub += 0x7FFFu + ((ub >> 16) & 1u);
    return (ua >> 16) | (ub & 0xFFFF0000u);
#endif
}

__device__ __forceinline__ short f2bf(float f) {
    unsigned u = __float_as_uint(f);
    u += 0x7FFFu + ((u >> 16) & 1u);
    return (short)(u >> 16);
}

__device__ __forceinline__ float bf2f(short s) {
    return __uint_as_float(((unsigned)(unsigned short)s) << 16);
}

// ---------------- Kernel 1: grouped 1x1 conv via MFMA ----------------
__global__ __launch_bounds__(TPB, 4) void qkv_mfma(
    const float* __restrict__ x,
    const float* __restrict__ Wq, const float* __restrict__ bq,
    const float* __restrict__ Wk, const float* __restrict__ bk,
    const float* __restrict__ Wv, const float* __restrict__ bv,
    short* __restrict__ qt, short* __restrict__ kt, short* __restrict__ v)
{
    const int bg = blockIdx.y, gh = bg & (NUM_G - 1);
    const int lane = threadIdx.x & 63, w = threadIdx.x >> 6;
    const int m = lane & 15, g = lane >> 4;

    const float* xb = x + (size_t)bg * HD * LSP;
    short* qtb = qt + (size_t)bg * LSP * HD;
    short* ktb = kt + (size_t)bg * LSP * HD;
    short* vb  = v  + (size_t)bg * HD * LSP;

    B8 wqf[2], wkf[2], wvf[2];
    float bqv[2], bkv[2], bvv[2][4];
#pragma unroll
    for (int h = 0; h < 2; ++h) {
        const int o = 16 * h + m;
        const float* wqp = Wq + (size_t)(gh * HD + o) * HD + 8 * g;
        const float* wkp = Wk + (size_t)(gh * HD + o) * HD + 8 * g;
        const float* wvp = Wv + (size_t)(gh * HD + o) * HD + 8 * g;
#pragma unroll
        for (int p = 0; p < 4; ++p) {
            wqf[h].u[p] = pk_bf16(wqp[2*p] * LOG2E, wqp[2*p+1] * LOG2E);
            wkf[h].u[p] = pk_bf16(wkp[2*p],         wkp[2*p+1]);
            wvf[h].u[p] = pk_bf16(wvp[2*p],         wvp[2*p+1]);
        }
        bqv[h] = bq[gh * HD + o] * LOG2E;
        bkv[h] = bk[gh * HD + o];
#pragma unroll
        for (int r = 0; r < 4; ++r)
            bvv[h][r] = bv[gh * HD + 16 * h + 4 * g + r];
    }

    const int l0 = blockIdx.x * 256 + w * 64;
    const f32x4 zero = {0.f, 0.f, 0.f, 0.f};
#pragma unroll
    for (int c = 0; c < 4; ++c) {
        const int lc = l0 + 16 * c;
        int lrow = lc + m; if (lrow >= LSP) lrow = LSP - 1;
        B8 xf;
#pragma unroll
        for (int p = 0; p < 4; ++p) {
            const float a0 = xb[(size_t)(8*g + 2*p)     * LSP + lrow];
            const float a1 = xb[(size_t)(8*g + 2*p + 1) * LSP + lrow];
            xf.u[p] = pk_bf16(a0, a1);
        }
#pragma unroll
        for (int h = 0; h < 2; ++h) {
            f32x4 cq = __builtin_amdgcn_mfma_f32_16x16x32_bf16(xf.h, wqf[h].h, zero, 0, 0, 0);
            f32x4 ck = __builtin_amdgcn_mfma_f32_16x16x32_bf16(xf.h, wkf[h].h, zero, 0, 0, 0);
            f32x4 cv = __builtin_amdgcn_mfma_f32_16x16x32_bf16(wvf[h].h, xf.h, zero, 0, 0, 0);
            const int lcol = lc + m;
#pragma unroll
            for (int r = 0; r < 4; ++r) {
                const int lr = lc + 4 * g + r;
                if (lr < LSP) {
                    qtb[(size_t)lr * HD + 16 * h + m] = f2bf(cq[r] + bqv[h]);
                    ktb[(size_t)lr * HD + 16 * h + m] = f2bf(ck[r] + bkv[h]);
                }
                if (lcol < LSP)
                    vb[(size_t)(16 * h + 4 * g + r) * LSP + lcol] = f2bf(cv[r] + bvv[h][r]);
            }
        }
    }
}

// ---------------- Kernel 2: Z over 64-j block; v *= 1/Z in-place ----------------
__global__ __launch_bounds__(TPB, 6) void z_mfma(
    const short* __restrict__ qt, const short* __restrict__ kt,
    short* __restrict__ v)
{
    const int bg = blockIdx.y;
    const int jb = blockIdx.x * 64;
    const int t = threadIdx.x;
    const int lane = t & 63, w = t >> 6, m = lane & 15, g = lane >> 4;

    const short* qtb = qt + (size_t)bg * LSP * HD;
    const short* ktb = kt + (size_t)bg * LSP * HD;
    short* vb = v + (size_t)bg * HD * LSP;

    bf16x8 aq[4];
#pragma unroll
    for (int jq = 0; jq < 4; ++jq)
        aq[jq] = *(const bf16x8*)(qtb + (size_t)(jb + 16 * jq + m) * HD + 8 * g);

    f32x4 zacc[4];
#pragma unroll
    for (int jq = 0; jq < 4; ++jq) zacc[jq] = (f32x4){0.f, 0.f, 0.f, 0.f};

    const f32x4 zero = {0.f, 0.f, 0.f, 0.f};
    for (int it = 0; it < 49; ++it) {
        const bf16x8 bkc = *(const bf16x8*)(ktb + (size_t)(it * 64 + 16 * w + m) * HD + 8 * g);
#pragma unroll
        for (int jq = 0; jq < 4; ++jq) {
            f32x4 c = __builtin_amdgcn_mfma_f32_16x16x32_bf16(aq[jq], bkc, zero, 0, 0, 0);
#pragma unroll
            for (int r = 0; r < 4; ++r) zacc[jq][r] += fast_exp2(c[r]);
        }
    }

    __shared__ float zl[64];
    if (t < 64) zl[t] = 0.f;
    __syncthreads();
#pragma unroll
    for (int jq = 0; jq < 4; ++jq) {
#pragma unroll
        for (int r = 0; r < 4; ++r) {
            float s = zacc[jq][r];
            s += __shfl_xor(s, 1); s += __shfl_xor(s, 2);
            s += __shfl_xor(s, 4); s += __shfl_xor(s, 8);
            if (m == 0) atomicAdd(&zl[16 * jq + 4 * g + r], s);
        }
    }
    __syncthreads();

    const int d0 = t >> 3;
    const int jl = (t & 7) * 8;
    float rzv[8];
#pragma unroll
    for (int e = 0; e < 8; ++e) rzv[e] = 1.0f / zl[jl + e];
    short* vp = vb + (size_t)d0 * LSP + jb + jl;
    bf16x8 vv = *(bf16x8*)vp;
    B8 o;
#pragma unroll
    for (int p = 0; p < 4; ++p)
        o.u[p] = pk_bf16(bf2f(vv[2*p]) * rzv[2*p], bf2f(vv[2*p+1]) * rzv[2*p+1]);
    *(bf16x8*)vp = o.h;
}

// ---------------- Kernel 3: out[d,k] = sum_j exp2(q'_j.k_k) * v'[d,j] + x ----------------
// grid 49x32 (64 k-cols/block). Wave w sweeps j-tiles {w, w+4, ...}; all 4 k-subtiles
// per wave (ILP). P transpose via wave-private XOR-swizzled LDS (conflict-free, R4-verified).
// Cross-wave partial reduction through LDS at the end.
__global__ __launch_bounds__(TPB, 5) void out_mfma(
    const short* __restrict__ qt, const short* __restrict__ kt,
    const short* __restrict__ v,
    const float* __restrict__ x, float* __restrict__ out)
{
    const int bg = blockIdx.y;
    const int k0 = blockIdx.x * 64;
    const int lane = threadIdx.x & 63, w = threadIdx.x >> 6;
    const int m = lane & 15, g = lane >> 4;

    const short* qtb = qt + (size_t)bg * LSP * HD;
    const short* ktb = kt + (size_t)bg * LSP * HD;
    const short* vb  = v  + (size_t)bg * HD * LSP;

    bf16x8 bk[4];
#pragma unroll
    for (int ks = 0; ks < 4; ++ks)
        bk[ks] = *(const bf16x8*)(ktb + (size_t)(k0 + 16 * ks + m) * HD + 8 * g);

    __shared__ unsigned lds[8192];          // 32KB: loop = [w][ks][512]; epilogue = float[4][2048]
    unsigned* pw = lds + w * 2048;
    const int t2 = 2 * m;
    const int cb = m * 32;

    const f32x4 zero = {0.f, 0.f, 0.f, 0.f};
    f32x4 acc[4][2];
#pragma unroll
    for (int ks = 0; ks < 4; ++ks) { acc[ks][0] = zero; acc[ks][1] = zero; }

    for (int jt = w; jt < 49; jt += 4) {
        const int j0 = jt * 64;

        const bf16x8 av0 = *(const bf16x8*)(vb + (size_t)m        * LSP + j0      + 8 * g);
        const bf16x8 av1 = *(const bf16x8*)(vb + (size_t)m        * LSP + j0 + 32 + 8 * g);
        const bf16x8 av2 = *(const bf16x8*)(vb + (size_t)(16 + m) * LSP + j0      + 8 * g);
        const bf16x8 av3 = *(const bf16x8*)(vb + (size_t)(16 + m) * LSP + j0 + 32 + 8 * g);

        bf16x8 aq[4];
#pragma unroll
        for (int jq = 0; jq < 4; ++jq)
            aq[jq] = *(const bf16x8*)(qtb + (size_t)(j0 + 16 * jq + m) * HD + 8 * g);

#pragma unroll
        for (int ks = 0; ks < 4; ++ks) {
#pragma unroll
            for (int jq = 0; jq < 4; ++jq) {
                const f32x4 e = __builtin_amdgcn_mfma_f32_16x16x32_bf16(aq[jq], bk[ks], zero, 0, 0, 0);
                uint2v w0;
                w0[0] = pk_bf16(fast_exp2(e[0]), fast_exp2(e[1]));
                w0[1] = pk_bf16(fast_exp2(e[2]), fast_exp2(e[3]));
                *(uint2v*)(pw + ks * 512 + cb + ((8 * jq + 2 * g) ^ t2)) = w0;
            }
        }

        const int blo0 = (4 * g)          ^ t2;
        const int blo1 = (4 * g + 2)      ^ t2;
        const int bhi0 = (16 + 4 * g)     ^ t2;
        const int bhi1 = (16 + 4 * g + 2) ^ t2;
#pragma unroll
        for (int ks = 0; ks < 4; ++ks) {
            U8 bplo, bphi;
            bplo.u[0] = *(uint2v*)(pw + ks * 512 + cb + blo0);
            bplo.u[1] = *(uint2v*)(pw + ks * 512 + cb + blo1);
            bphi.u[0] = *(uint2v*)(pw + ks * 512 + cb + bhi0);
            bphi.u[1] = *(uint2v*)(pw + ks * 512 + cb + bhi1);
            acc[ks][0] = __builtin_amdgcn_mfma_f32_16x16x32_bf16(av0, bplo.h, acc[ks][0], 0, 0, 0);
            acc[ks][0] = __builtin_amdgcn_mfma_f32_16x16x32_bf16(av1, bphi.h, acc[ks][0], 0, 0, 0);
            acc[ks][1] = __builtin_amdgcn_mfma_f32_16x16x32_bf16(av2, bplo.h, acc[ks][1], 0, 0, 0);
            acc[ks][1] = __builtin_amdgcn_mfma_f32_16x16x32_bf16(av3, bphi.h, acc[ks][1], 0, 0, 0);
        }
    }

    // ---- cross-wave reduction of partial out tiles ----
    __syncthreads();
    float* fl = (float*)lds;
#pragma unroll
    for (int ks = 0; ks < 4; ++ks)
#pragma unroll
        for (int ds = 0; ds < 2; ++ds)
#pragma unroll
            for (int r = 0; r < 4; ++r) {
                const int d = 16 * ds + 4 * g + r;
                fl[w * 2048 + d * 64 + 16 * ks + m] = acc[ks][ds][r];
            }
    __syncthreads();

    const int t = threadIdx.x;
    const int i0 = t * 8;
    f32x4 s0 = *(f32x4*)(fl + i0);
    f32x4 s1 = *(f32x4*)(fl + i0 + 4);
#pragma unroll
    for (int wi = 1; wi < 4; ++wi) {
        const f32x4 a0 = *(f32x4*)(fl + wi * 2048 + i0);
        const f32x4 a1 = *(f32x4*)(fl + wi * 2048 + i0 + 4);
#pragma unroll
        for (int r = 0; r < 4; ++r) { s0[r] += a0[r]; s1[r] += a1[r]; }
    }
    const int d = t >> 3;
    const int kloc = (t & 7) * 8;
    const size_t idx = (size_t)bg * HD * LSP + (size_t)d * LSP + k0 + kloc;
    const f32x4 x0 = *(const f32x4*)(x + idx);
    const f32x4 x1 = *(const f32x4*)(x + idx + 4);
#pragma unroll
    for (int r = 0; r < 4; ++r) { s0[r] += x0[r]; s1[r] += x1[r]; }
    *(f32x4*)(out + idx)     = s0;
    *(f32x4*)(out + idx + 4) = s1;
}

extern "C" void kernel_launch(void* const* d_in, const int* in_sizes, int n_in,
                              void* d_out, int out_size, void* d_ws, size_t ws_size,
                              hipStream_t stream) {
    const float* x  = (const float*)d_in[0];
    const float* Wq = (const float*)d_in[1];
    const float* bq = (const float*)d_in[2];
    const float* Wk = (const float*)d_in[3];
    const float* bk = (const float*)d_in[4];
    const float* Wv = (const float*)d_in[5];
    const float* bv = (const float*)d_in[6];
    float* out = (float*)d_out;

    const size_t QSZ = (size_t)BG * HD * LSP;
    short* qt = (short*)d_ws;
    short* kt = qt + QSZ;
    short* v  = kt + QSZ;

    qkv_mfma<<<dim3(13, BG), TPB, 0, stream>>>(x, Wq, bq, Wk, bk, Wv, bv, qt, kt, v);
    z_mfma  <<<dim3(49, BG), TPB, 0, stream>>>(qt, kt, v);
    out_mfma<<<dim3(49, BG), TPB, 0, stream>>>(qt, kt, v, x, out);
}

// Round 8
// 203.385 us; speedup vs baseline: 1.1745x; 1.1745x over previous
//
#include <hip/hip_runtime.h>

// Problem constants (B=4, C=256, H=W=56, heads=8)
#define NUM_G 8
#define HD    32
#define LSP   3136            // 56*56 = 49*64 exactly
#define BG    32
#define TPB   256
#define LOG2E 1.4426950408889634f

typedef short bf16x8 __attribute__((ext_vector_type(8)));
typedef float f32x4  __attribute__((ext_vector_type(4)));
typedef unsigned uint2v __attribute__((ext_vector_type(2)));
typedef unsigned uint4v __attribute__((ext_vector_type(4)));

union B8 { bf16x8 h; uint4v u; };
union U8 { bf16x8 h; uint2v u[2]; };

// ---- single-instruction 2^x via compiler-known lowering (hazards handled) ----
// [R7 evidence: inlines to one v_exp_f32 — VALUBusy dropped 57->41%]
extern "C" __device__ float __ocml_native_exp2_f32(float);
__device__ __forceinline__ float fast_exp2(float x) {
#if __has_builtin(__builtin_amdgcn_exp2f)
    return __builtin_amdgcn_exp2f(x);
#else
    return __ocml_native_exp2_f32(x);     // lowers to llvm.amdgcn.exp2 -> v_exp_f32
#endif
}

// ---- packed f32x2 -> bf16x2 ----
__device__ __forceinline__ unsigned pk_bf16(float a, float b) {
#if __has_builtin(__builtin_amdgcn_cvt_pk_bf16_f32)
    typedef __bf16 bf16x2_t __attribute__((ext_vector_type(2)));
    bf16x2_t r = __builtin_amdgcn_cvt_pk_bf16_f32(a, b);
    unsigned u; __builtin_memcpy(&u, &r, 4); return u;
#else
    unsigned ua = __float_as_uint(a); ua += 0x7FFFu + ((ua >> 16) & 1u);
    unsigned ub = __float_as_uint(b); ub += 0x7FFFu + ((ub >> 16) & 1u);
    return (ua >> 16) | (ub & 0xFFFF0000u);
#endif
}

__device__ __forceinline__ short f2bf(float f) {
    unsigned u = __float_as_uint(f);
    u += 0x7FFFu + ((u >> 16) & 1u);
    return (short)(u >> 16);
}

__device__ __forceinline__ float bf2f(short s) {
    return __uint_as_float(((unsigned)(unsigned short)s) << 16);
}

// ---------------- Kernel 1: grouped 1x1 conv via MFMA ----------------
__global__ __launch_bounds__(TPB, 4) void qkv_mfma(
    const float* __restrict__ x,
    const float* __restrict__ Wq, const float* __restrict__ bq,
    const float* __restrict__ Wk, const float* __restrict__ bk,
    const float* __restrict__ Wv, const float* __restrict__ bv,
    short* __restrict__ qt, short* __restrict__ kt, short* __restrict__ v)
{
    const int bg = blockIdx.y, gh = bg & (NUM_G - 1);
    const int lane = threadIdx.x & 63, w = threadIdx.x >> 6;
    const int m = lane & 15, g = lane >> 4;

    const float* xb = x + (size_t)bg * HD * LSP;
    short* qtb = qt + (size_t)bg * LSP * HD;
    short* ktb = kt + (size_t)bg * LSP * HD;
    short* vb  = v  + (size_t)bg * HD * LSP;

    B8 wqf[2], wkf[2], wvf[2];
    float bqv[2], bkv[2], bvv[2][4];
#pragma unroll
    for (int h = 0; h < 2; ++h) {
        const int o = 16 * h + m;
        const float* wqp = Wq + (size_t)(gh * HD + o) * HD + 8 * g;
        const float* wkp = Wk + (size_t)(gh * HD + o) * HD + 8 * g;
        const float* wvp = Wv + (size_t)(gh * HD + o) * HD + 8 * g;
#pragma unroll
        for (int p = 0; p < 4; ++p) {
            wqf[h].u[p] = pk_bf16(wqp[2*p] * LOG2E, wqp[2*p+1] * LOG2E);
            wkf[h].u[p] = pk_bf16(wkp[2*p],         wkp[2*p+1]);
            wvf[h].u[p] = pk_bf16(wvp[2*p],         wvp[2*p+1]);
        }
        bqv[h] = bq[gh * HD + o] * LOG2E;
        bkv[h] = bk[gh * HD + o];
#pragma unroll
        for (int r = 0; r < 4; ++r)
            bvv[h][r] = bv[gh * HD + 16 * h + 4 * g + r];
    }

    const int l0 = blockIdx.x * 256 + w * 64;
    const f32x4 zero = {0.f, 0.f, 0.f, 0.f};
#pragma unroll
    for (int c = 0; c < 4; ++c) {
        const int lc = l0 + 16 * c;
        int lrow = lc + m; if (lrow >= LSP) lrow = LSP - 1;
        B8 xf;
#pragma unroll
        for (int p = 0; p < 4; ++p) {
            const float a0 = xb[(size_t)(8*g + 2*p)     * LSP + lrow];
            const float a1 = xb[(size_t)(8*g + 2*p + 1) * LSP + lrow];
            xf.u[p] = pk_bf16(a0, a1);
        }
#pragma unroll
        for (int h = 0; h < 2; ++h) {
            f32x4 cq = __builtin_amdgcn_mfma_f32_16x16x32_bf16(xf.h, wqf[h].h, zero, 0, 0, 0);
            f32x4 ck = __builtin_amdgcn_mfma_f32_16x16x32_bf16(xf.h, wkf[h].h, zero, 0, 0, 0);
            f32x4 cv = __builtin_amdgcn_mfma_f32_16x16x32_bf16(wvf[h].h, xf.h, zero, 0, 0, 0);
            const int lcol = lc + m;
#pragma unroll
            for (int r = 0; r < 4; ++r) {
                const int lr = lc + 4 * g + r;
                if (lr < LSP) {
                    qtb[(size_t)lr * HD + 16 * h + m] = f2bf(cq[r] + bqv[h]);
                    ktb[(size_t)lr * HD + 16 * h + m] = f2bf(ck[r] + bkv[h]);
                }
                if (lcol < LSP)
                    vb[(size_t)(16 * h + 4 * g + r) * LSP + lcol] = f2bf(cv[r] + bvv[h][r]);
            }
        }
    }
}

// ---------------- Kernel 2: Z over 64-j block; v *= 1/Z in-place ----------------
__global__ __launch_bounds__(TPB, 6) void z_mfma(
    const short* __restrict__ qt, const short* __restrict__ kt,
    short* __restrict__ v)
{
    const int bg = blockIdx.y;
    const int jb = blockIdx.x * 64;
    const int t = threadIdx.x;
    const int lane = t & 63, w = t >> 6, m = lane & 15, g = lane >> 4;

    const short* qtb = qt + (size_t)bg * LSP * HD;
    const short* ktb = kt + (size_t)bg * LSP * HD;
    short* vb = v + (size_t)bg * HD * LSP;

    bf16x8 aq[4];
#pragma unroll
    for (int jq = 0; jq < 4; ++jq)
        aq[jq] = *(const bf16x8*)(qtb + (size_t)(jb + 16 * jq + m) * HD + 8 * g);

    f32x4 zacc[4];
#pragma unroll
    for (int jq = 0; jq < 4; ++jq) zacc[jq] = (f32x4){0.f, 0.f, 0.f, 0.f};

    const f32x4 zero = {0.f, 0.f, 0.f, 0.f};
    for (int it = 0; it < 49; ++it) {
        const bf16x8 bkc = *(const bf16x8*)(ktb + (size_t)(it * 64 + 16 * w + m) * HD + 8 * g);
#pragma unroll
        for (int jq = 0; jq < 4; ++jq) {
            f32x4 c = __builtin_amdgcn_mfma_f32_16x16x32_bf16(aq[jq], bkc, zero, 0, 0, 0);
#pragma unroll
            for (int r = 0; r < 4; ++r) zacc[jq][r] += fast_exp2(c[r]);
        }
    }

    __shared__ float zl[64];
    if (t < 64) zl[t] = 0.f;
    __syncthreads();
#pragma unroll
    for (int jq = 0; jq < 4; ++jq) {
#pragma unroll
        for (int r = 0; r < 4; ++r) {
            float s = zacc[jq][r];
            s += __shfl_xor(s, 1); s += __shfl_xor(s, 2);
            s += __shfl_xor(s, 4); s += __shfl_xor(s, 8);
            if (m == 0) atomicAdd(&zl[16 * jq + 4 * g + r], s);
        }
    }
    __syncthreads();

    const int d0 = t >> 3;
    const int jl = (t & 7) * 8;
    float rzv[8];
#pragma unroll
    for (int e = 0; e < 8; ++e) rzv[e] = 1.0f / zl[jl + e];
    short* vp = vb + (size_t)d0 * LSP + jb + jl;
    bf16x8 vv = *(bf16x8*)vp;
    B8 o;
#pragma unroll
    for (int p = 0; p < 4; ++p)
        o.u[p] = pk_bf16(bf2f(vv[2*p]) * rzv[2*p], bf2f(vv[2*p+1]) * rzv[2*p+1]);
    *(bf16x8*)vp = o.h;
}

// ---------------- Kernel 3: out[d,k] = sum_j exp2(q'_j.k_k) * v'[d,j] + x ----------------
// grid 49x32 (64 k-cols/block). Wave w sweeps j-tiles {w, w+4, ...}; all 4 k-subtiles
// per wave (ILP). P transpose via wave-private XOR-swizzled LDS (conflict-free, R4-verified).
// launch_bounds (256,4): (256,5) squeezed VGPRs -> scratch spills (R7: WRITE 14->47MB).
__global__ __launch_bounds__(TPB, 4) void out_mfma(
    const short* __restrict__ qt, const short* __restrict__ kt,
    const short* __restrict__ v,
    const float* __restrict__ x, float* __restrict__ out)
{
    const int bg = blockIdx.y;
    const int k0 = blockIdx.x * 64;
    const int lane = threadIdx.x & 63, w = threadIdx.x >> 6;
    const int m = lane & 15, g = lane >> 4;

    const short* qtb = qt + (size_t)bg * LSP * HD;
    const short* ktb = kt + (size_t)bg * LSP * HD;
    const short* vb  = v  + (size_t)bg * HD * LSP;

    bf16x8 bk[4];
#pragma unroll
    for (int ks = 0; ks < 4; ++ks)
        bk[ks] = *(const bf16x8*)(ktb + (size_t)(k0 + 16 * ks + m) * HD + 8 * g);

    __shared__ unsigned lds[8192];          // 32KB: loop = [w][ks][512]; epilogue = float[4][2048]
    unsigned* pw = lds + w * 2048;
    const int t2 = 2 * m;
    const int cb = m * 32;

    const f32x4 zero = {0.f, 0.f, 0.f, 0.f};
    f32x4 acc[4][2];
#pragma unroll
    for (int ks = 0; ks < 4; ++ks) { acc[ks][0] = zero; acc[ks][1] = zero; }

    for (int jt = w; jt < 49; jt += 4) {
        const int j0 = jt * 64;

        const bf16x8 av0 = *(const bf16x8*)(vb + (size_t)m        * LSP + j0      + 8 * g);
        const bf16x8 av1 = *(const bf16x8*)(vb + (size_t)m        * LSP + j0 + 32 + 8 * g);
        const bf16x8 av2 = *(const bf16x8*)(vb + (size_t)(16 + m) * LSP + j0      + 8 * g);
        const bf16x8 av3 = *(const bf16x8*)(vb + (size_t)(16 + m) * LSP + j0 + 32 + 8 * g);

        bf16x8 aq[4];
#pragma unroll
        for (int jq = 0; jq < 4; ++jq)
            aq[jq] = *(const bf16x8*)(qtb + (size_t)(j0 + 16 * jq + m) * HD + 8 * g);

#pragma unroll
        for (int ks = 0; ks < 4; ++ks) {
#pragma unroll
            for (int jq = 0; jq < 4; ++jq) {
                const f32x4 e = __builtin_amdgcn_mfma_f32_16x16x32_bf16(aq[jq], bk[ks], zero, 0, 0, 0);
                uint2v w0;
                w0[0] = pk_bf16(fast_exp2(e[0]), fast_exp2(e[1]));
                w0[1] = pk_bf16(fast_exp2(e[2]), fast_exp2(e[3]));
                *(uint2v*)(pw + ks * 512 + cb + ((8 * jq + 2 * g) ^ t2)) = w0;
            }
        }

        const int blo0 = (4 * g)          ^ t2;
        const int blo1 = (4 * g + 2)      ^ t2;
        const int bhi0 = (16 + 4 * g)     ^ t2;
        const int bhi1 = (16 + 4 * g + 2) ^ t2;
#pragma unroll
        for (int ks = 0; ks < 4; ++ks) {
            U8 bplo, bphi;
            bplo.u[0] = *(uint2v*)(pw + ks * 512 + cb + blo0);
            bplo.u[1] = *(uint2v*)(pw + ks * 512 + cb + blo1);
            bphi.u[0] = *(uint2v*)(pw + ks * 512 + cb + bhi0);
            bphi.u[1] = *(uint2v*)(pw + ks * 512 + cb + bhi1);
            acc[ks][0] = __builtin_amdgcn_mfma_f32_16x16x32_bf16(av0, bplo.h, acc[ks][0], 0, 0, 0);
            acc[ks][0] = __builtin_amdgcn_mfma_f32_16x16x32_bf16(av1, bphi.h, acc[ks][0], 0, 0, 0);
            acc[ks][1] = __builtin_amdgcn_mfma_f32_16x16x32_bf16(av2, bplo.h, acc[ks][1], 0, 0, 0);
            acc[ks][1] = __builtin_amdgcn_mfma_f32_16x16x32_bf16(av3, bphi.h, acc[ks][1], 0, 0, 0);
        }
    }

    // ---- cross-wave reduction of partial out tiles ----
    __syncthreads();
    float* fl = (float*)lds;
#pragma unroll
    for (int ks = 0; ks < 4; ++ks)
#pragma unroll
        for (int ds = 0; ds < 2; ++ds)
#pragma unroll
            for (int r = 0; r < 4; ++r) {
                const int d = 16 * ds + 4 * g + r;
                fl[w * 2048 + d * 64 + 16 * ks + m] = acc[ks][ds][r];
            }
    __syncthreads();

    const int t = threadIdx.x;
    const int i0 = t * 8;
    f32x4 s0 = *(f32x4*)(fl + i0);
    f32x4 s1 = *(f32x4*)(fl + i0 + 4);
#pragma unroll
    for (int wi = 1; wi < 4; ++wi) {
        const f32x4 a0 = *(f32x4*)(fl + wi * 2048 + i0);
        const f32x4 a1 = *(f32x4*)(fl + wi * 2048 + i0 + 4);
#pragma unroll
        for (int r = 0; r < 4; ++r) { s0[r] += a0[r]; s1[r] += a1[r]; }
    }
    const int d = t >> 3;
    const int kloc = (t & 7) * 8;
    const size_t idx = (size_t)bg * HD * LSP + (size_t)d * LSP + k0 + kloc;
    const f32x4 x0 = *(const f32x4*)(x + idx);
    const f32x4 x1 = *(const f32x4*)(x + idx + 4);
#pragma unroll
    for (int r = 0; r < 4; ++r) { s0[r] += x0[r]; s1[r] += x1[r]; }
    *(f32x4*)(out + idx)     = s0;
    *(f32x4*)(out + idx + 4) = s1;
}

extern "C" void kernel_launch(void* const* d_in, const int* in_sizes, int n_in,
                              void* d_out, int out_size, void* d_ws, size_t ws_size,
                              hipStream_t stream) {
    const float* x  = (const float*)d_in[0];
    const float* Wq = (const float*)d_in[1];
    const float* bq = (const float*)d_in[2];
    const float* Wk = (const float*)d_in[3];
    const float* bk = (const float*)d_in[4];
    const float* Wv = (const float*)d_in[5];
    const float* bv = (const float*)d_in[6];
    float* out = (float*)d_out;

    const size_t QSZ = (size_t)BG * HD * LSP;
    short* qt = (short*)d_ws;
    short* kt = qt + QSZ;
    short* v  = kt + QSZ;

    qkv_mfma<<<dim3(13, BG), TPB, 0, stream>>>(x, Wq, bq, Wk, bk, Wv, bv, qt, kt, v);
    z_mfma  <<<dim3(49, BG), TPB, 0, stream>>>(qt, kt, v);
    out_mfma<<<dim3(49, BG), TPB, 0, stream>>>(qt, kt, v, x, out);
}

// Round 9
// 200.178 us; speedup vs baseline: 1.1933x; 1.0160x over previous
//
#include <hip/hip_runtime.h>

// Problem constants (B=4, C=256, H=W=56, heads=8)
#define NUM_G 8
#define HD    32
#define LSP   3136            // 56*56 = 49*64 exactly
#define BG    32
#define TPB   256
#define LOG2E 1.4426950408889634f

typedef short bf16x8 __attribute__((ext_vector_type(8)));
typedef float f32x4  __attribute__((ext_vector_type(4)));
typedef unsigned uint2v __attribute__((ext_vector_type(2)));
typedef unsigned uint4v __attribute__((ext_vector_type(4)));

union B8 { bf16x8 h; uint4v u; };
union U8 { bf16x8 h; uint2v u[2]; };

// single v_exp_f32 (R5/R8 A/B showed exp2f already lowers natively; keep explicit)
extern "C" __device__ float __ocml_native_exp2_f32(float);
__device__ __forceinline__ float fast_exp2(float x) {
#if __has_builtin(__builtin_amdgcn_exp2f)
    return __builtin_amdgcn_exp2f(x);
#else
    return __ocml_native_exp2_f32(x);
#endif
}

__device__ __forceinline__ unsigned pk_bf16(float a, float b) {
#if __has_builtin(__builtin_amdgcn_cvt_pk_bf16_f32)
    typedef __bf16 bf16x2_t __attribute__((ext_vector_type(2)));
    bf16x2_t r = __builtin_amdgcn_cvt_pk_bf16_f32(a, b);
    unsigned u; __builtin_memcpy(&u, &r, 4); return u;
#else
    unsigned ua = __float_as_uint(a); ua += 0x7FFFu + ((ua >> 16) & 1u);
    unsigned ub = __float_as_uint(b); ub += 0x7FFFu + ((ub >> 16) & 1u);
    return (ua >> 16) | (ub & 0xFFFF0000u);
#endif
}

__device__ __forceinline__ short f2bf(float f) {
    unsigned u = __float_as_uint(f);
    u += 0x7FFFu + ((u >> 16) & 1u);
    return (short)(u >> 16);
}

__device__ __forceinline__ float bf2f(short s) {
    return __uint_as_float(((unsigned)(unsigned short)s) << 16);
}

// ---------------- Kernel 1: grouped 1x1 conv via MFMA ----------------
__global__ __launch_bounds__(TPB, 4) void qkv_mfma(
    const float* __restrict__ x,
    const float* __restrict__ Wq, const float* __restrict__ bq,
    const float* __restrict__ Wk, const float* __restrict__ bk,
    const float* __restrict__ Wv, const float* __restrict__ bv,
    short* __restrict__ qt, short* __restrict__ kt, short* __restrict__ v)
{
    const int bg = blockIdx.y, gh = bg & (NUM_G - 1);
    const int lane = threadIdx.x & 63, w = threadIdx.x >> 6;
    const int m = lane & 15, g = lane >> 4;

    const float* xb = x + (size_t)bg * HD * LSP;
    short* qtb = qt + (size_t)bg * LSP * HD;
    short* ktb = kt + (size_t)bg * LSP * HD;
    short* vb  = v  + (size_t)bg * HD * LSP;

    B8 wqf[2], wkf[2], wvf[2];
    float bqv[2], bkv[2], bvv[2][4];
#pragma unroll
    for (int h = 0; h < 2; ++h) {
        const int o = 16 * h + m;
        const float* wqp = Wq + (size_t)(gh * HD + o) * HD + 8 * g;
        const float* wkp = Wk + (size_t)(gh * HD + o) * HD + 8 * g;
        const float* wvp = Wv + (size_t)(gh * HD + o) * HD + 8 * g;
#pragma unroll
        for (int p = 0; p < 4; ++p) {
            wqf[h].u[p] = pk_bf16(wqp[2*p] * LOG2E, wqp[2*p+1] * LOG2E);
            wkf[h].u[p] = pk_bf16(wkp[2*p],         wkp[2*p+1]);
            wvf[h].u[p] = pk_bf16(wvp[2*p],         wvp[2*p+1]);
        }
        bqv[h] = bq[gh * HD + o] * LOG2E;
        bkv[h] = bk[gh * HD + o];
#pragma unroll
        for (int r = 0; r < 4; ++r)
            bvv[h][r] = bv[gh * HD + 16 * h + 4 * g + r];
    }

    const int l0 = blockIdx.x * 256 + w * 64;
    const f32x4 zero = {0.f, 0.f, 0.f, 0.f};
#pragma unroll
    for (int c = 0; c < 4; ++c) {
        const int lc = l0 + 16 * c;
        int lrow = lc + m; if (lrow >= LSP) lrow = LSP - 1;
        B8 xf;
#pragma unroll
        for (int p = 0; p < 4; ++p) {
            const float a0 = xb[(size_t)(8*g + 2*p)     * LSP + lrow];
            const float a1 = xb[(size_t)(8*g + 2*p + 1) * LSP + lrow];
            xf.u[p] = pk_bf16(a0, a1);
        }
#pragma unroll
        for (int h = 0; h < 2; ++h) {
            f32x4 cq = __builtin_amdgcn_mfma_f32_16x16x32_bf16(xf.h, wqf[h].h, zero, 0, 0, 0);
            f32x4 ck = __builtin_amdgcn_mfma_f32_16x16x32_bf16(xf.h, wkf[h].h, zero, 0, 0, 0);
            f32x4 cv = __builtin_amdgcn_mfma_f32_16x16x32_bf16(wvf[h].h, xf.h, zero, 0, 0, 0);
            const int lcol = lc + m;
#pragma unroll
            for (int r = 0; r < 4; ++r) {
                const int lr = lc + 4 * g + r;
                if (lr < LSP) {
                    qtb[(size_t)lr * HD + 16 * h + m] = f2bf(cq[r] + bqv[h]);
                    ktb[(size_t)lr * HD + 16 * h + m] = f2bf(ck[r] + bkv[h]);
                }
                if (lcol < LSP)
                    vb[(size_t)(16 * h + 4 * g + r) * LSP + lcol] = f2bf(cv[r] + bvv[h][r]);
            }
        }
    }
}

// ---------------- Kernel 2: Z over 64-j block; v *= 1/Z in-place ----------------
__global__ __launch_bounds__(TPB, 6) void z_mfma(
    const short* __restrict__ qt, const short* __restrict__ kt,
    short* __restrict__ v)
{
    const int bg = blockIdx.y;
    const int jb = blockIdx.x * 64;
    const int t = threadIdx.x;
    const int lane = t & 63, w = t >> 6, m = lane & 15, g = lane >> 4;

    const short* qtb = qt + (size_t)bg * LSP * HD;
    const short* ktb = kt + (size_t)bg * LSP * HD;
    short* vb = v + (size_t)bg * HD * LSP;

    bf16x8 aq[4];
#pragma unroll
    for (int jq = 0; jq < 4; ++jq)
        aq[jq] = *(const bf16x8*)(qtb + (size_t)(jb + 16 * jq + m) * HD + 8 * g);

    f32x4 zacc[4];
#pragma unroll
    for (int jq = 0; jq < 4; ++jq) zacc[jq] = (f32x4){0.f, 0.f, 0.f, 0.f};

    const f32x4 zero = {0.f, 0.f, 0.f, 0.f};
    for (int it = 0; it < 49; ++it) {
        const bf16x8 bkc = *(const bf16x8*)(ktb + (size_t)(it * 64 + 16 * w + m) * HD + 8 * g);
#pragma unroll
        for (int jq = 0; jq < 4; ++jq) {
            f32x4 c = __builtin_amdgcn_mfma_f32_16x16x32_bf16(aq[jq], bkc, zero, 0, 0, 0);
#pragma unroll
            for (int r = 0; r < 4; ++r) zacc[jq][r] += fast_exp2(c[r]);
        }
    }

    __shared__ float zl[64];
    if (t < 64) zl[t] = 0.f;
    __syncthreads();
#pragma unroll
    for (int jq = 0; jq < 4; ++jq) {
#pragma unroll
        for (int r = 0; r < 4; ++r) {
            float s = zacc[jq][r];
            s += __shfl_xor(s, 1); s += __shfl_xor(s, 2);
            s += __shfl_xor(s, 4); s += __shfl_xor(s, 8);
            if (m == 0) atomicAdd(&zl[16 * jq + 4 * g + r], s);
        }
    }
    __syncthreads();

    const int d0 = t >> 3;
    const int jl = (t & 7) * 8;
    float rzv[8];
#pragma unroll
    for (int e = 0; e < 8; ++e) rzv[e] = 1.0f / zl[jl + e];
    short* vp = vb + (size_t)d0 * LSP + jb + jl;
    bf16x8 vv = *(bf16x8*)vp;
    B8 o;
#pragma unroll
    for (int p = 0; p < 4; ++p)
        o.u[p] = pk_bf16(bf2f(vv[2*p]) * rzv[2*p], bf2f(vv[2*p+1]) * rzv[2*p+1]);
    *(bf16x8*)vp = o.h;
}

// ---------------- Kernel 3: out[d,k] = sum_j exp2(q'_j.k_k) * v'[d,j] + x ----------------
// 16KB LDS/block (was 32KB): P staged per ks-PAIR, region reused for the second pair
// (same-wave DS ordering makes the WAR safe). Occupancy cap moves 5 -> 8 blocks/CU.
// Swizzle scheme unchanged (conflict-free, R4-verified). Epilogue in 2 stages of 16KB.
__global__ __launch_bounds__(TPB, 4) void out_mfma(
    const short* __restrict__ qt, const short* __restrict__ kt,
    const short* __restrict__ v,
    const float* __restrict__ x, float* __restrict__ out)
{
    const int bg = blockIdx.y;
    const int k0 = blockIdx.x * 64;
    const int lane = threadIdx.x & 63, w = threadIdx.x >> 6;
    const int m = lane & 15, g = lane >> 4;

    const short* qtb = qt + (size_t)bg * LSP * HD;
    const short* ktb = kt + (size_t)bg * LSP * HD;
    const short* vb  = v  + (size_t)bg * HD * LSP;

    bf16x8 bk[4];
#pragma unroll
    for (int ks = 0; ks < 4; ++ks)
        bk[ks] = *(const bf16x8*)(ktb + (size_t)(k0 + 16 * ks + m) * HD + 8 * g);

    __shared__ unsigned lds[4096];          // 16KB: loop = [w][ks2][512]; epilogue float[4][1024]
    unsigned* pw = lds + w * 1024;
    const int t2 = 2 * m;
    const int cb = m * 32;

    const f32x4 zero = {0.f, 0.f, 0.f, 0.f};
    f32x4 acc[4][2];
#pragma unroll
    for (int ks = 0; ks < 4; ++ks) { acc[ks][0] = zero; acc[ks][1] = zero; }

    for (int jt = w; jt < 49; jt += 4) {
        const int j0 = jt * 64;

        const bf16x8 av0 = *(const bf16x8*)(vb + (size_t)m        * LSP + j0      + 8 * g);
        const bf16x8 av1 = *(const bf16x8*)(vb + (size_t)m        * LSP + j0 + 32 + 8 * g);
        const bf16x8 av2 = *(const bf16x8*)(vb + (size_t)(16 + m) * LSP + j0      + 8 * g);
        const bf16x8 av3 = *(const bf16x8*)(vb + (size_t)(16 + m) * LSP + j0 + 32 + 8 * g);

        bf16x8 aq[4];
#pragma unroll
        for (int jq = 0; jq < 4; ++jq)
            aq[jq] = *(const bf16x8*)(qtb + (size_t)(j0 + 16 * jq + m) * HD + 8 * g);

        const int blo0 = (4 * g)          ^ t2;
        const int blo1 = (4 * g + 2)      ^ t2;
        const int bhi0 = (16 + 4 * g)     ^ t2;
        const int bhi1 = (16 + 4 * g + 2) ^ t2;

#pragma unroll
        for (int kh = 0; kh < 2; ++kh) {
#pragma unroll
            for (int ks2 = 0; ks2 < 2; ++ks2) {
                const int ks = 2 * kh + ks2;
#pragma unroll
                for (int jq = 0; jq < 4; ++jq) {
                    const f32x4 e = __builtin_amdgcn_mfma_f32_16x16x32_bf16(aq[jq], bk[ks], zero, 0, 0, 0);
                    uint2v w0;
                    w0[0] = pk_bf16(fast_exp2(e[0]), fast_exp2(e[1]));
                    w0[1] = pk_bf16(fast_exp2(e[2]), fast_exp2(e[3]));
                    *(uint2v*)(pw + ks2 * 512 + cb + ((8 * jq + 2 * g) ^ t2)) = w0;
                }
            }
#pragma unroll
            for (int ks2 = 0; ks2 < 2; ++ks2) {
                const int ks = 2 * kh + ks2;
                U8 bplo, bphi;
                bplo.u[0] = *(uint2v*)(pw + ks2 * 512 + cb + blo0);
                bplo.u[1] = *(uint2v*)(pw + ks2 * 512 + cb + blo1);
                bphi.u[0] = *(uint2v*)(pw + ks2 * 512 + cb + bhi0);
                bphi.u[1] = *(uint2v*)(pw + ks2 * 512 + cb + bhi1);
                acc[ks][0] = __builtin_amdgcn_mfma_f32_16x16x32_bf16(av0, bplo.h, acc[ks][0], 0, 0, 0);
                acc[ks][0] = __builtin_amdgcn_mfma_f32_16x16x32_bf16(av1, bphi.h, acc[ks][0], 0, 0, 0);
                acc[ks][1] = __builtin_amdgcn_mfma_f32_16x16x32_bf16(av2, bplo.h, acc[ks][1], 0, 0, 0);
                acc[ks][1] = __builtin_amdgcn_mfma_f32_16x16x32_bf16(av3, bphi.h, acc[ks][1], 0, 0, 0);
            }
        }
    }

    // ---- cross-wave reduction, 2 stages of 16KB (32d x 32k per stage) ----
    const int t = threadIdx.x;
    float* fl = (float*)lds;
    const size_t bgb = (size_t)bg * HD * LSP;
#pragma unroll
    for (int s = 0; s < 2; ++s) {
        __syncthreads();                    // s=0: P regions done; s=1: stage-0 reads done
#pragma unroll
        for (int ks2 = 0; ks2 < 2; ++ks2) {
            const int ks = 2 * s + ks2;
#pragma unroll
            for (int ds = 0; ds < 2; ++ds)
#pragma unroll
                for (int r = 0; r < 4; ++r) {
                    const int d = 16 * ds + 4 * g + r;
                    fl[w * 1024 + d * 32 + 16 * ks2 + m] = acc[ks][ds][r];
                }
        }
        __syncthreads();
        const int d = t >> 3;               // 0..31
        const int kloc = (t & 7) * 4;       // 0..28
        f32x4 sv = *(f32x4*)(fl + d * 32 + kloc);
#pragma unroll
        for (int wi = 1; wi < 4; ++wi) {
            const f32x4 a = *(f32x4*)(fl + wi * 1024 + d * 32 + kloc);
#pragma unroll
            for (int r = 0; r < 4; ++r) sv[r] += a[r];
        }
        const size_t idx = bgb + (size_t)d * LSP + k0 + 32 * s + kloc;
        const f32x4 xv = *(const f32x4*)(x + idx);
#pragma unroll
        for (int r = 0; r < 4; ++r) sv[r] += xv[r];
        *(f32x4*)(out + idx) = sv;
    }
}

extern "C" void kernel_launch(void* const* d_in, const int* in_sizes, int n_in,
                              void* d_out, int out_size, void* d_ws, size_t ws_size,
                              hipStream_t stream) {
    const float* x  = (const float*)d_in[0];
    const float* Wq = (const float*)d_in[1];
    const float* bq = (const float*)d_in[2];
    const float* Wk = (const float*)d_in[3];
    const float* bk = (const float*)d_in[4];
    const float* Wv = (const float*)d_in[5];
    const float* bv = (const float*)d_in[6];
    float* out = (float*)d_out;

    const size_t QSZ = (size_t)BG * HD * LSP;
    short* qt = (short*)d_ws;
    short* kt = qt + QSZ;
    short* v  = kt + QSZ;

    qkv_mfma<<<dim3(13, BG), TPB, 0, stream>>>(x, Wq, bq, Wk, bk, Wv, bv, qt, kt, v);
    z_mfma  <<<dim3(49, BG), TPB, 0, stream>>>(qt, kt, v);
    out_mfma<<<dim3(49, BG), TPB, 0, stream>>>(qt, kt, v, x, out);
}